// Round 6
// baseline (250.097 us; speedup 1.0000x reference)
//
#include <hip/hip_runtime.h>
#include <hip/hip_bf16.h>

#define NN   100000
#define KD   500
#define KP   512    // K padded (W zero-filled)
#define HID  64
#define LWS  264    // LDS row stride (bf16 elems) for a 256-wide K chunk
#define GS   24     // g row stride (floats): B at cols 0..9, C at cols 12..21
#define NXCD 8

typedef short frag8 __attribute__((ext_vector_type(8)));
typedef float f32x4 __attribute__((ext_vector_type(4)));

static __device__ __forceinline__ unsigned short f2b(float f) {
    return __builtin_bit_cast(unsigned short, __float2bfloat16(f));
}

// ---------------- Kernel 0: W1 fp32 -> bf16, zero-padded to K=512 ----------------
__global__ __launch_bounds__(256) void k0_w1bf(const float* __restrict__ W1,
                                               unsigned short* __restrict__ W1bf)
{
    const int i = blockIdx.x * 256 + threadIdx.x;   // 0..32767
    const int c = i >> 9;        // col 0..63
    const int k = i & 511;
    const float v = (k < KD) ? W1[c * KD + k] : 0.f;
    W1bf[i] = f2b(v);
}

// ---------------- Kernel 1: h = relu(x @ W1^T), bf16 MFMA ----------------
__global__ __launch_bounds__(256, 4) void k1_mfma(const float* __restrict__ x,
                                                  const unsigned short* __restrict__ W1bf,
                                                  float* __restrict__ h, int n)
{
    __shared__ unsigned short lw[64 * LWS];
    const int tid   = threadIdx.x;
    const int lane  = tid & 63;
    const int wid   = tid >> 6;
    const int l15   = lane & 15;
    const int l4    = lane >> 4;     // 0..3
    const int koffl = 8 * l4;        // lane's k sub-offset within a 32-k step

    const long rowBlk = (long)blockIdx.x * 64;
    long ra = rowBlk + wid * 16 + l15;
    if (ra >= n) ra = n - 1;                 // clamp; stores are guarded
    const float* xp = x + ra * KD + koffl;

    f32x4 acc[4] = {};
    const float4 z = make_float4(0.f, 0.f, 0.f, 0.f);

    for (int c = 0; c < 2; ++c) {
        if (c) __syncthreads();
        #pragma unroll
        for (int it = 0; it < 8; ++it) {
            const int idx = tid + it * 256;      // 0..2047
            const int r   = idx >> 5;            // 0..63
            const int q   = idx & 31;            // ushort8 index
            *(uint4*)&lw[r * LWS + q * 8] =
                *(const uint4*)&W1bf[r * KP + c * 256 + q * 8];
        }
        __syncthreads();

        int k0 = c * 256;
        float4 lo = (k0 + koffl     < KD) ? *(const float4*)(xp + k0)     : z;
        float4 hi = (k0 + koffl + 4 < KD) ? *(const float4*)(xp + k0 + 4) : z;

        #pragma unroll
        for (int ks = 0; ks < 8; ++ks) {
            float4 nlo = z, nhi = z;
            if (ks < 7) {
                const int kn = c * 256 + (ks + 1) * 32;
                nlo = (kn + koffl     < KD) ? *(const float4*)(xp + kn)     : z;
                nhi = (kn + koffl + 4 < KD) ? *(const float4*)(xp + kn + 4) : z;
            }
            frag8 a;
            a[0]=f2b(lo.x); a[1]=f2b(lo.y); a[2]=f2b(lo.z); a[3]=f2b(lo.w);
            a[4]=f2b(hi.x); a[5]=f2b(hi.y); a[6]=f2b(hi.z); a[7]=f2b(hi.w);
            const int koffw = ks * 32 + koffl;
            #pragma unroll
            for (int g = 0; g < 4; ++g) {
                const frag8 b = *(const frag8*)&lw[(g * 16 + l15) * LWS + koffw];
                acc[g] = __builtin_amdgcn_mfma_f32_16x16x32_bf16(a, b, acc[g], 0, 0, 0);
            }
            lo = nlo; hi = nhi;
        }
    }

    #pragma unroll
    for (int r = 0; r < 4; ++r) {
        const long row = rowBlk + wid * 16 + l4 * 4 + r;
        if (row < n) {
            #pragma unroll
            for (int g = 0; g < 4; ++g)
                h[row * HID + g * 16 + l15] = fmaxf(acc[g][r], 0.f);
        }
    }
}

// ---------------- Kernel 2: projections ----------------
__global__ __launch_bounds__(256) void k2_proj(const float* __restrict__ h,
                                               const float* __restrict__ Wf,
                                               float* __restrict__ out,
                                               float* __restrict__ g, int n)
{
    __shared__ float lwf[10 * 196];
    const int tid = threadIdx.x;
    for (int idx = tid; idx < 480; idx += 256) {
        const int j = idx / 48;
        const int q = idx - j * 48;
        const float4 v = *(const float4*)&Wf[j * 192 + 4 * q];
        *(float4*)&lwf[j * 196 + 4 * q] = v;
    }
    __syncthreads();

    const long row = (long)blockIdx.x * 8 + (tid >> 5);
    const int  j   = tid & 31;
    if (row < n && j < 30) {
        const int wrow = (j < 10) ? j : ((j < 20) ? j - 10 : j - 20);
        const int coff = (j < 10) ? 0 : ((j < 20) ? 64 : 128);
        const float* wp = &lwf[wrow * 196 + coff];
        const float* hp = &h[row * HID];
        float s = 0.f;
        #pragma unroll
        for (int q = 0; q < 16; ++q) {
            const float4 hv = *(const float4*)&hp[4 * q];
            const float4 wv = *(const float4*)&wp[4 * q];
            s += hv.x * wv.x + hv.y * wv.y + hv.z * wv.z + hv.w * wv.w;
        }
        if (j < 10)      out[row * 10 + j] = s;
        else if (j < 20) g[row * GS + (j - 10)] = s;
        else             g[row * GS + 12 + (j - 20)] = s;
    }
}

// ---------------- Kernel 3a: scatter into per-XCD replicas (TCC-local atomics) ----
// Each XCD accumulates into its private 4 MB replica (selected by HW_REG_XCC_ID),
// so workgroup-scope atomics (no sc1 -> executed at the XCD's own L2) are correct.
__global__ __launch_bounds__(256) void k_scatter_rep(const int* __restrict__ src1,
                                                     const int* __restrict__ dst1,
                                                     const float* __restrict__ val1, int n1,
                                                     const int* __restrict__ src2,
                                                     const int* __restrict__ dst2,
                                                     const float* __restrict__ val2, int nt,
                                                     const float* __restrict__ g,
                                                     float* __restrict__ rep)
{
    const int t = blockIdx.x * 256 + threadIdx.x;
    if (t >= nt) return;
    const bool h1 = t < n1;
    const int  tt = h1 ? t : t - n1;
    const int  e  = (int)((unsigned)tt / 10u);
    const int  j  = tt - 10 * e;
    const int* sp = h1 ? src1 : src2;
    const int* dp = h1 ? dst1 : dst2;
    const float* vp = h1 ? val1 : val2;
    const int   s = sp[e];
    const int   d = dp[e];
    const float v = vp[e];
    const float c = v * g[(size_t)s * GS + (h1 ? 0 : 12) + j];

    unsigned xcc;
    asm volatile("s_getreg_b32 %0, hwreg(HW_REG_XCC_ID)" : "=s"(xcc));
    float* r = rep + (size_t)(xcc & (NXCD - 1)) * (NN * 10);
    __hip_atomic_fetch_add(&r[d * 10 + j], c, __ATOMIC_RELAXED,
                           __HIP_MEMORY_SCOPE_WORKGROUP);
}

// ---------------- Kernel 3b: fallback direct scatter (agent-scope atomics) -------
__global__ __launch_bounds__(256) void k_scatter_dir(const int* __restrict__ src1,
                                                     const int* __restrict__ dst1,
                                                     const float* __restrict__ val1, int n1,
                                                     const int* __restrict__ src2,
                                                     const int* __restrict__ dst2,
                                                     const float* __restrict__ val2, int nt,
                                                     const float* __restrict__ g,
                                                     float* __restrict__ out)
{
    const int t = blockIdx.x * 256 + threadIdx.x;
    if (t >= nt) return;
    const bool h1 = t < n1;
    const int  tt = h1 ? t : t - n1;
    const int  e  = (int)((unsigned)tt / 10u);
    const int  j  = tt - 10 * e;
    const int* sp = h1 ? src1 : src2;
    const int* dp = h1 ? dst1 : dst2;
    const float* vp = h1 ? val1 : val2;
    unsafeAtomicAdd(&out[(size_t)dp[e] * 10 + j],
                    vp[e] * g[(size_t)sp[e] * GS + (h1 ? 0 : 12) + j]);
}

// ---------------- Kernel 4: out += sum of 8 replicas ----------------
__global__ __launch_bounds__(256) void k_reduce(const float* __restrict__ rep,
                                                float* __restrict__ out)
{
    const int i = blockIdx.x * 256 + threadIdx.x;     // float4 index
    if (i >= NN * 10 / 4) return;
    float4 s = *(const float4*)&out[4 * i];
    #pragma unroll
    for (int r = 0; r < NXCD; ++r) {
        const float4 a = *(const float4*)&rep[(size_t)r * (NN * 10) + 4 * i];
        s.x += a.x; s.y += a.y; s.z += a.z; s.w += a.w;
    }
    *(float4*)&out[4 * i] = s;
}

extern "C" void kernel_launch(void* const* d_in, const int* in_sizes, int n_in,
                              void* d_out, int out_size, void* d_ws, size_t ws_size,
                              hipStream_t stream)
{
    const float* x    = (const float*)d_in[0];
    const float* W1   = (const float*)d_in[1];
    const float* Wf   = (const float*)d_in[2];
    const int*   src1 = (const int*)d_in[3];
    const int*   dst1 = (const int*)d_in[4];
    const float* val1 = (const float*)d_in[5];
    const int*   src2 = (const int*)d_in[6];
    const int*   dst2 = (const int*)d_in[7];
    const float* val2 = (const float*)d_in[8];
    const int nnz1 = in_sizes[3];
    const int nnz2 = in_sizes[6];
    const int n = NN;

    unsigned short* W1bf = (unsigned short*)d_ws;                  // 64 KB
    float* h   = (float*)((char*)d_ws + 64 * KP * 2);              // [NN][64]  25.6 MB
    float* g   = h + (size_t)NN * HID;                             // [NN][24]   9.6 MB
    float* rep = g + (size_t)NN * GS;                              // 8x[NN][10] 32 MB
    float* out = (float*)d_out;                                    // [NN][10]

    const size_t ws_need = (size_t)64 * KP * 2 + (size_t)NN * HID * 4
                         + (size_t)NN * GS * 4 + (size_t)NXCD * NN * 10 * 4;

    k0_w1bf<<<128, 256, 0, stream>>>(W1, W1bf);
    k1_mfma<<<(n + 63) / 64, 256, 0, stream>>>(x, W1bf, h, n);
    k2_proj<<<(n + 7) / 8, 256, 0, stream>>>(h, Wf, out, g, n);

    const int n1 = 10 * nnz1;
    const int nt = n1 + 10 * nnz2;
    if (ws_size >= ws_need) {
        hipMemsetAsync(rep, 0, (size_t)NXCD * NN * 10 * 4, stream);
        k_scatter_rep<<<(nt + 255) / 256, 256, 0, stream>>>(src1, dst1, val1, n1,
                                                            src2, dst2, val2, nt, g, rep);
        k_reduce<<<(NN * 10 / 4 + 255) / 256, 256, 0, stream>>>(rep, out);
    } else {
        k_scatter_dir<<<(nt + 255) / 256, 256, 0, stream>>>(src1, dst1, val1, n1,
                                                            src2, dst2, val2, nt, g, out);
    }
}